// Round 2
// baseline (381.403 us; speedup 1.0000x reference)
//
#include <hip/hip_runtime.h>
#include <math.h>

// Problem constants (B,S,H,D,P fixed by the reference).
#define B_ 16
#define S_ 512
#define H_ 12
#define D_ 768
#define P_ 256
#define K_ 51
#define CH_ 16            // s-rows per k2 chunk
#define NCHUNK_ (S_/CH_)  // 32

// Monotonic float->uint key: larger float <=> larger unsigned.
__device__ __forceinline__ unsigned okey(float f) {
  unsigned u = __float_as_uint(f);
  return (u & 0x80000000u) ? ~u : (u | 0x80000000u);
}

// One block per (b,t) attention row: head-average, top-K select, scatter 1/cnt.
// Radix select: per-wave privatized double-buffered histograms, 2 barriers/pass,
// early exit when the tie bucket exactly fills the remaining slots.
__global__ __launch_bounds__(256) void k1_topk_weights(
    const float* __restrict__ attn, float* __restrict__ w) {
  const int bt = blockIdx.x;
  const int b = bt >> 9;            // S_ == 512
  const int t = bt & (S_ - 1);
  const int tid = threadIdx.x;
  const int wave = tid >> 6;

  __shared__ unsigned keys[S_];
  __shared__ __align__(16) unsigned hist[2][4][256];  // [buf][wave][bin]
  __shared__ int ipar[4];  // [0]=pos count, [1]=digit, [2]=count above, [3]=tie count

  // zero hist[0] (pass-0 buffer): 256 threads x 16 B = 4 KB
  ((uint4*)&hist[0][0][0])[tid] = uint4{0u, 0u, 0u, 0u};
  if (tid == 0) ipar[0] = 0;

  // --- head-average: each thread owns elements 2*tid, 2*tid+1 ---
  const float* base = attn + (((size_t)b * H_) * S_ + t) * S_;
  float2 acc = make_float2(0.f, 0.f);
  #pragma unroll
  for (int h = 0; h < H_; ++h) {
    const float2 v = *(const float2*)(base + (size_t)h * S_ * S_ + 2 * tid);
    acc.x += v.x; acc.y += v.y;
  }
  const float a0 = acc.x * (1.0f / (float)H_);
  const float a1 = acc.y * (1.0f / (float)H_);
  const unsigned k0 = okey(a0);
  const unsigned k1v = okey(a1);
  keys[2 * tid] = k0;
  keys[2 * tid + 1] = k1v;

  // --- positive count via ballot (1 atomic per wave, not per thread) ---
  {
    const unsigned long long m0 = __ballot(a0 > 0.f);
    const unsigned long long m1 = __ballot(a1 > 0.f);
    if ((tid & 63) == 0) atomicAdd(&ipar[0], __popcll(m0) + __popcll(m1));
  }
  __syncthreads();
  const int p = ipar[0];

  bool sel0, sel1;
  float invcnt;
  if (p >= 1 && p < K_) {
    // kept set == all positive entries (they are all inside the top-K)
    sel0 = (a0 > 0.f);
    sel1 = (a1 > 0.f);
    invcnt = 1.0f / (float)p;
  } else {
    // p >= K (all top-K positive) or p == 0 (keep forced): exact top-K radix select.
    unsigned prefix = 0;
    int remaining = K_;
    int tieCnt = 0;
    int exited = 0;
    unsigned exitm = 0;
    for (int pass = 0; pass < 4; ++pass) {
      const int shift = 24 - 8 * pass;
      const unsigned pm = (pass == 0) ? 0u : (0xFFFFFFFFu << (shift + 8));
      const int cur = pass & 1, nxt = cur ^ 1;
      // phase A: histogram into this pass's buffer; zero the other buffer.
      if ((k0 & pm) == prefix) atomicAdd(&hist[cur][wave][(k0 >> shift) & 255u], 1u);
      if ((k1v & pm) == prefix) atomicAdd(&hist[cur][wave][(k1v >> shift) & 255u], 1u);
      ((uint4*)&hist[nxt][0][0])[tid] = uint4{0u, 0u, 0u, 0u};
      __syncthreads();
      // phase B: single wave merges 4 copies, suffix-scans, finds crossing locally.
      if (wave == 0) {
        const int lane = tid;  // 0..63, owns bins 4*lane .. 4*lane+3
        unsigned c0 = 0, c1 = 0, c2 = 0, c3 = 0;
        #pragma unroll
        for (int wv = 0; wv < 4; ++wv) {
          const uint4 v = ((const uint4*)&hist[cur][wv][0])[lane];
          c0 += v.x; c1 += v.y; c2 += v.z; c3 += v.w;
        }
        const unsigned loc = c0 + c1 + c2 + c3;
        unsigned suf = loc;
        #pragma unroll
        for (int off = 1; off < 64; off <<= 1) {
          const unsigned v = __shfl_down(suf, off, 64);
          if (lane + off < 64) suf += v;
        }
        const unsigned after = suf - loc;       // suffix of lanes > lane
        const unsigned s3 = after + c3;
        const unsigned s2 = s3 + c2;
        const unsigned s1 = s2 + c1;
        const unsigned s0 = s1 + c0;
        const unsigned rem = (unsigned)remaining;
        // exactly one bin crosses (s is non-increasing, s_top >= rem >= 1 > 0 = s_end)
        if (s0 >= rem && s1 < rem)    { ipar[1] = 4*lane+0; ipar[2] = (int)s1;    ipar[3] = (int)(s0 - s1); }
        if (s1 >= rem && s2 < rem)    { ipar[1] = 4*lane+1; ipar[2] = (int)s2;    ipar[3] = (int)(s1 - s2); }
        if (s2 >= rem && s3 < rem)    { ipar[1] = 4*lane+2; ipar[2] = (int)s3;    ipar[3] = (int)(s2 - s3); }
        if (s3 >= rem && after < rem) { ipar[1] = 4*lane+3; ipar[2] = (int)after; ipar[3] = (int)(s3 - after); }
      }
      __syncthreads();
      const int dc = ipar[1];
      prefix |= ((unsigned)dc) << shift;
      remaining -= ipar[2];
      tieCnt = ipar[3];
      if (tieCnt == remaining) {   // all ties kept -> selection decided now
        exited = 1;
        exitm = 0xFFFFFFFFu << shift;
        break;                      // uniform break
      }
    }
    if (exited) {
      sel0 = (k0 & exitm) >= prefix;
      sel1 = (k1v & exitm) >= prefix;
    } else {
      // tieCnt > remaining at the last pass: keep `remaining` lowest-index ties (jax order)
      const unsigned T = prefix;
      sel0 = (k0 > T);
      sel1 = (k1v > T);
      if (k0 == T) {
        int r = 0;
        for (int s2i = 0; s2i < 2 * tid; ++s2i) r += (keys[s2i] == T);
        if (r < remaining) sel0 = true;
      }
      if (k1v == T) {
        int r = 0;
        for (int s2i = 0; s2i < 2 * tid + 1; ++s2i) r += (keys[s2i] == T);
        if (r < remaining) sel1 = true;
      }
    }
    invcnt = 1.0f / (float)K_;
  }

  float* wrow = w + b * S_;
  if (sel0) atomicAdd(&wrow[2 * tid], invcnt);
  if (sel1) atomicAdd(&wrow[2 * tid + 1], invcnt);
}

// x[b,d] = sum_s coef[b,s] * hidden[b,s,d],  coef = (eta + (1-eta)*w)/S
__global__ __launch_bounds__(192) void k2_weighted_sum(
    const float* __restrict__ hidden, const float* __restrict__ w,
    const float* __restrict__ node_eta, float* __restrict__ x) {
  const int chunk = blockIdx.x;
  const int b = blockIdx.y;
  const int tid = threadIdx.x;  // 0..191 -> d = 4*tid .. 4*tid+3 (D_ = 768)
  __shared__ float coef[CH_];
  if (tid < CH_) {
    const float eta = node_eta[0];
    const float wv = w[b * S_ + chunk * CH_ + tid];
    coef[tid] = (eta + (1.0f - eta) * wv) * (1.0f / (float)S_);
  }
  __syncthreads();
  const float* hb = hidden + ((size_t)b * S_ + (size_t)chunk * CH_) * D_ + 4 * tid;
  float4 acc = make_float4(0.f, 0.f, 0.f, 0.f);
  #pragma unroll
  for (int s = 0; s < CH_; ++s) {
    const float4 v = *(const float4*)(hb + (size_t)s * D_);
    const float c = coef[s];
    acc.x += c * v.x; acc.y += c * v.y; acc.z += c * v.z; acc.w += c * v.w;
  }
  float* xp = x + b * D_ + 4 * tid;
  atomicAdd(xp + 0, acc.x);
  atomicAdd(xp + 1, acc.y);
  atomicAdd(xp + 2, acc.z);
  atomicAdd(xp + 3, acc.w);
}

// vec = x@W_node + b_node; t=tanh(vec); o = t@W_fc + b_fc; LayerNorm(o)
__global__ __launch_bounds__(256) void k3_final(
    const float* __restrict__ x, const float* __restrict__ W_node,
    const float* __restrict__ b_node, const float* __restrict__ W_fc,
    const float* __restrict__ b_fc, const float* __restrict__ gamma,
    const float* __restrict__ beta, float* __restrict__ out) {
  const int b = blockIdx.x;
  const int tid = threadIdx.x;  // == output channel p
  __shared__ float xs[D_];
  __shared__ float ts[P_];
  __shared__ float red[4];

  for (int d = tid; d < D_; d += 256) xs[d] = x[b * D_ + d];
  __syncthreads();

  float v = b_node[tid];
  #pragma unroll 8
  for (int d = 0; d < D_; ++d) v += xs[d] * W_node[d * P_ + tid];
  ts[tid] = tanhf(v);
  __syncthreads();

  float o = b_fc[tid];
  #pragma unroll 8
  for (int q = 0; q < P_; ++q) o += ts[q] * W_fc[q * P_ + tid];

  // block mean
  float s = o;
  #pragma unroll
  for (int off = 32; off > 0; off >>= 1) s += __shfl_down(s, off, 64);
  const int wave = tid >> 6, lane = tid & 63;
  if (lane == 0) red[wave] = s;
  __syncthreads();
  const float mu = (red[0] + red[1] + red[2] + red[3]) * (1.0f / (float)P_);
  __syncthreads();
  // block variance (two-pass, matches reference)
  const float dv = o - mu;
  float s2 = dv * dv;
  #pragma unroll
  for (int off = 32; off > 0; off >>= 1) s2 += __shfl_down(s2, off, 64);
  if (lane == 0) red[wave] = s2;
  __syncthreads();
  const float var = (red[0] + red[1] + red[2] + red[3]) * (1.0f / (float)P_);
  const float inv = 1.0f / sqrtf(var + 1e-5f);
  out[b * P_ + tid] = dv * inv * gamma[tid] + beta[tid];
}

extern "C" void kernel_launch(void* const* d_in, const int* in_sizes, int n_in,
                              void* d_out, int out_size, void* d_ws, size_t ws_size,
                              hipStream_t stream) {
  (void)in_sizes; (void)n_in; (void)out_size; (void)ws_size;
  const float* hidden   = (const float*)d_in[0];  // [B,S,D]
  const float* attn     = (const float*)d_in[1];  // [B,H,S,S]
  /* d_in[2] = length (== S, unused) */
  const float* W_node   = (const float*)d_in[3];  // [D,P]
  const float* b_node   = (const float*)d_in[4];  // [P]
  const float* node_eta = (const float*)d_in[5];  // [1]
  const float* W_fc     = (const float*)d_in[6];  // [P,P]
  const float* b_fc     = (const float*)d_in[7];  // [P]
  const float* gamma    = (const float*)d_in[8];  // [P]
  const float* beta     = (const float*)d_in[9];  // [P]
  float* out = (float*)d_out;                     // [B,P] fp32

  float* w = (float*)d_ws;        // B_*S_ floats (edge-weight sums per source node)
  float* x = w + B_ * S_;         // B_*D_ floats (coef-weighted hidden sums)
  hipMemsetAsync(d_ws, 0, (size_t)(B_ * S_ + B_ * D_) * sizeof(float), stream);

  k1_topk_weights<<<B_ * S_, 256, 0, stream>>>(attn, w);
  k2_weighted_sum<<<dim3(NCHUNK_, B_), 192, 0, stream>>>(hidden, w, node_eta, x);
  k3_final<<<B_, 256, 0, stream>>>(x, W_node, b_node, W_fc, b_fc, gamma, beta, out);
}

// Round 3
// 340.669 us; speedup vs baseline: 1.1196x; 1.1196x over previous
//
#include <hip/hip_runtime.h>
#include <math.h>

// Problem constants (B,S,H,D,P fixed by the reference).
#define B_ 16
#define S_ 512
#define H_ 12
#define D_ 768
#define P_ 256
#define K_ 51
#define CH_ 16            // s-rows per k2 chunk
#define NCHUNK_ (S_/CH_)  // 32

// Wave-synchronous LDS ordering: wait for all outstanding LDS ops, and stop
// the compiler from reordering LDS accesses across this point.
#define WAVE_SYNC() asm volatile("s_waitcnt lgkmcnt(0)" ::: "memory")

// Monotonic float->uint key: larger float <=> larger unsigned.
__device__ __forceinline__ unsigned okey(float f) {
  unsigned u = __float_as_uint(f);
  return (u & 0x80000000u) ? ~u : (u | 0x80000000u);
}

// One WAVE per (b,t) attention row: head-average, top-K select, scatter 1/cnt.
// 8 elements/lane held in registers; per-wave private LDS histogram; shuffle
// suffix-scan; ballot broadcast. No __syncthreads anywhere.
__global__ __launch_bounds__(256) void k1_topk_weights(
    const float* __restrict__ attn, float* __restrict__ w) {
  const int tid = threadIdx.x;
  const int wv = tid >> 6;
  const int lane = tid & 63;
  const int bt = blockIdx.x * 4 + wv;
  const int b = bt >> 9;            // S_ == 512
  const int t = bt & (S_ - 1);

  __shared__ __align__(16) unsigned hist[4][256];  // per-wave private

  // zero own histogram (lane owns bins 4*lane..4*lane+3)
  *(uint4*)&hist[wv][4 * lane] = uint4{0u, 0u, 0u, 0u};

  // --- head-average: lane owns columns {4*lane+i, 256+4*lane+i} ---
  const float* base = attn + (((size_t)b * H_) * S_ + t) * S_;
  float a[8] = {0.f, 0.f, 0.f, 0.f, 0.f, 0.f, 0.f, 0.f};
  #pragma unroll
  for (int h = 0; h < H_; ++h) {
    const float* r = base + (size_t)h * (S_ * S_);
    const float4 u = *(const float4*)(r + 4 * lane);
    const float4 v = *(const float4*)(r + 256 + 4 * lane);
    a[0] += u.x; a[1] += u.y; a[2] += u.z; a[3] += u.w;
    a[4] += v.x; a[5] += v.y; a[6] += v.z; a[7] += v.w;
  }
  unsigned k[8];
  #pragma unroll
  for (int i = 0; i < 8; ++i) {
    a[i] *= (1.0f / (float)H_);
    k[i] = okey(a[i]);
  }

  // --- row-wide positive count via ballots (wave-uniform result) ---
  int p = 0;
  #pragma unroll
  for (int i = 0; i < 8; ++i) p += __popcll(__ballot(a[i] > 0.f));

  bool sel[8];
  float invcnt;
  if (p >= 1 && p < K_) {
    // kept set == all positive entries (all inside the top-K)
    #pragma unroll
    for (int i = 0; i < 8; ++i) sel[i] = (a[i] > 0.f);
    invcnt = 1.0f / (float)p;
  } else {
    // exact top-K radix select (8-bit digits), wave-synchronous.
    unsigned prefix = 0;
    int remaining = K_;
    int tieCnt = 0;
    bool exited = false;
    unsigned exitm = 0;
    for (int pass = 0; pass < 4; ++pass) {
      const int shift = 24 - 8 * pass;
      const unsigned pm = (pass == 0) ? 0u : (0xFFFFFFFFu << (shift + 8));
      WAVE_SYNC();  // prior zeroing complete before new atomics
      #pragma unroll
      for (int i = 0; i < 8; ++i)
        if ((k[i] & pm) == prefix)
          atomicAdd(&hist[wv][(k[i] >> shift) & 255u], 1u);
      WAVE_SYNC();  // histogram complete before reading
      const uint4 c4 = *(uint4*)&hist[wv][4 * lane];
      *(uint4*)&hist[wv][4 * lane] = uint4{0u, 0u, 0u, 0u};  // for next pass
      const unsigned loc = c4.x + c4.y + c4.z + c4.w;
      unsigned suf = loc;
      #pragma unroll
      for (int off = 1; off < 64; off <<= 1) {
        const unsigned vv = __shfl_down(suf, off, 64);
        if (lane + off < 64) suf += vv;
      }
      const unsigned after = suf - loc;  // suffix of lanes > lane
      const unsigned s3 = after + c4.w;
      const unsigned s2 = s3 + c4.z;
      const unsigned s1 = s2 + c4.y;
      const unsigned s0 = s1 + c4.x;
      const unsigned rem = (unsigned)remaining;
      int dig = 0, abv = 0, tie = 0;
      bool found = false;
      if (s0 >= rem && s1 < rem)         { dig = 4*lane+0; abv = (int)s1;    tie = (int)(s0 - s1);    found = true; }
      else if (s1 >= rem && s2 < rem)    { dig = 4*lane+1; abv = (int)s2;    tie = (int)(s1 - s2);    found = true; }
      else if (s2 >= rem && s3 < rem)    { dig = 4*lane+2; abv = (int)s3;    tie = (int)(s2 - s3);    found = true; }
      else if (s3 >= rem && after < rem) { dig = 4*lane+3; abv = (int)after; tie = (int)(s3 - after); found = true; }
      const unsigned long long fm = __ballot(found);
      const int src = __ffsll((unsigned long long)fm) - 1;
      dig = __shfl(dig, src, 64);
      abv = __shfl(abv, src, 64);
      tie = __shfl(tie, src, 64);
      prefix |= ((unsigned)dig) << shift;
      remaining -= abv;
      tieCnt = tie;
      if (tieCnt == remaining) {  // all ties kept -> selection decided now
        exited = true;
        exitm = (shift == 0) ? 0xFFFFFFFFu : (0xFFFFFFFFu << shift);
        break;                    // wave-uniform
      }
    }
    if (exited) {
      #pragma unroll
      for (int i = 0; i < 8; ++i) sel[i] = (k[i] & exitm) >= prefix;
    } else {
      // tieCnt > remaining at final pass: keep `remaining` lowest-index ties.
      const unsigned T = prefix;
      unsigned long long m[8];
      #pragma unroll
      for (int i = 0; i < 8; ++i) m[i] = __ballot(k[i] == T);
      const unsigned long long lt = ((unsigned long long)1 << lane) - 1ull;
      int fh = 0;
      #pragma unroll
      for (int i = 0; i < 4; ++i) fh += __popcll(m[i]);
      #pragma unroll
      for (int i = 0; i < 8; ++i) {
        sel[i] = (k[i] > T);
        if (k[i] == T) {
          int r = 0;
          if (i < 4) {
            #pragma unroll
            for (int i2 = 0; i2 < 4; ++i2) r += __popcll(m[i2] & lt);
            for (int i2 = 0; i2 < i; ++i2) r += (int)((m[i2] >> lane) & 1ull);
          } else {
            r = fh;
            #pragma unroll
            for (int i2 = 4; i2 < 8; ++i2) r += __popcll(m[i2] & lt);
            for (int i2 = 4; i2 < i; ++i2) r += (int)((m[i2] >> lane) & 1ull);
          }
          if (r < remaining) sel[i] = true;
        }
      }
    }
    invcnt = 1.0f / (float)K_;
  }

  float* wrow = w + b * S_;
  #pragma unroll
  for (int i = 0; i < 8; ++i) {
    const int col = (i < 4) ? (4 * lane + i) : (256 + 4 * lane + (i - 4));
    if (sel[i]) atomicAdd(&wrow[col], invcnt);
  }
}

// x[b,d] = sum_s coef[b,s] * hidden[b,s,d],  coef = (eta + (1-eta)*w)/S
__global__ __launch_bounds__(192) void k2_weighted_sum(
    const float* __restrict__ hidden, const float* __restrict__ w,
    const float* __restrict__ node_eta, float* __restrict__ x) {
  const int chunk = blockIdx.x;
  const int b = blockIdx.y;
  const int tid = threadIdx.x;  // 0..191 -> d = 4*tid .. 4*tid+3 (D_ = 768)
  __shared__ float coef[CH_];
  if (tid < CH_) {
    const float eta = node_eta[0];
    const float wv = w[b * S_ + chunk * CH_ + tid];
    coef[tid] = (eta + (1.0f - eta) * wv) * (1.0f / (float)S_);
  }
  __syncthreads();
  const float* hb = hidden + ((size_t)b * S_ + (size_t)chunk * CH_) * D_ + 4 * tid;
  float4 acc = make_float4(0.f, 0.f, 0.f, 0.f);
  #pragma unroll
  for (int s = 0; s < CH_; ++s) {
    const float4 v = *(const float4*)(hb + (size_t)s * D_);
    const float c = coef[s];
    acc.x += c * v.x; acc.y += c * v.y; acc.z += c * v.z; acc.w += c * v.w;
  }
  float* xp = x + b * D_ + 4 * tid;
  atomicAdd(xp + 0, acc.x);
  atomicAdd(xp + 1, acc.y);
  atomicAdd(xp + 2, acc.z);
  atomicAdd(xp + 3, acc.w);
}

// k3a: t[b,p] = tanh(x[b,:]@W_node[:,p] + b_node[p]) for a 32-col slice.
// grid (8, B), block 256 = 16 float2-cols x 16 d-groups of 48.
__global__ __launch_bounds__(256) void k3a_tanh_matvec(
    const float* __restrict__ x, const float* __restrict__ W_node,
    const float* __restrict__ b_node, float* __restrict__ tbuf) {
  const int j = blockIdx.x;   // 32-column slice
  const int b = blockIdx.y;
  const int tid = threadIdx.x;
  const int pp = tid & 15;    // float2 column pair
  const int g = tid >> 4;     // d-group
  __shared__ float xs[D_];
  __shared__ float part[16][32];
  for (int d = tid; d < D_; d += 256) xs[d] = x[b * D_ + d];
  __syncthreads();
  const float* Wp = W_node + 32 * j + 2 * pp;
  float2 acc = make_float2(0.f, 0.f);
  const int d0 = 48 * g;
  #pragma unroll 8
  for (int dd = 0; dd < 48; ++dd) {
    const int d = d0 + dd;
    const float2 wv = *(const float2*)(Wp + (size_t)d * P_);
    const float xv = xs[d];
    acc.x += xv * wv.x; acc.y += xv * wv.y;
  }
  *(float2*)&part[g][2 * pp] = acc;
  __syncthreads();
  if (tid < 32) {
    float s = 0.f;
    #pragma unroll
    for (int gg = 0; gg < 16; ++gg) s += part[gg][tid];
    const int pcol = 32 * j + tid;
    tbuf[b * P_ + pcol] = tanhf(s + b_node[pcol]);
  }
}

// k3b: o[b,p] = t[b,:]@W_fc[:,p] + b_fc[p] for a 64-col slice.
// grid (4, B), block 256 = 32 float2-cols x 8 q-groups of 32.
__global__ __launch_bounds__(256) void k3b_fc(
    const float* __restrict__ tbuf, const float* __restrict__ W_fc,
    const float* __restrict__ b_fc, float* __restrict__ obuf) {
  const int j = blockIdx.x;
  const int b = blockIdx.y;
  const int tid = threadIdx.x;
  const int pp = tid & 31;
  const int g = tid >> 5;
  __shared__ float ts[P_];
  __shared__ float part[8][64];
  ts[tid] = tbuf[b * P_ + tid];
  __syncthreads();
  const float* Wp = W_fc + 64 * j + 2 * pp;
  float2 acc = make_float2(0.f, 0.f);
  const int q0 = 32 * g;
  #pragma unroll 8
  for (int qq = 0; qq < 32; ++qq) {
    const int q = q0 + qq;
    const float2 wv = *(const float2*)(Wp + (size_t)q * P_);
    const float tv = ts[q];
    acc.x += tv * wv.x; acc.y += tv * wv.y;
  }
  *(float2*)&part[g][2 * pp] = acc;
  __syncthreads();
  if (tid < 64) {
    float s = 0.f;
    #pragma unroll
    for (int gg = 0; gg < 8; ++gg) s += part[gg][tid];
    const int pcol = 64 * j + tid;
    obuf[b * P_ + pcol] = s + b_fc[pcol];
  }
}

// k3c: LayerNorm over P per batch row.
__global__ __launch_bounds__(256) void k3c_layernorm(
    const float* __restrict__ obuf, const float* __restrict__ gamma,
    const float* __restrict__ beta, float* __restrict__ out) {
  const int b = blockIdx.x;
  const int tid = threadIdx.x;
  __shared__ float red[4];
  const float o = obuf[b * P_ + tid];
  float s = o;
  #pragma unroll
  for (int off = 32; off > 0; off >>= 1) s += __shfl_down(s, off, 64);
  const int wave = tid >> 6, lane = tid & 63;
  if (lane == 0) red[wave] = s;
  __syncthreads();
  const float mu = (red[0] + red[1] + red[2] + red[3]) * (1.0f / (float)P_);
  __syncthreads();
  const float dv = o - mu;
  float s2 = dv * dv;
  #pragma unroll
  for (int off = 32; off > 0; off >>= 1) s2 += __shfl_down(s2, off, 64);
  if (lane == 0) red[wave] = s2;
  __syncthreads();
  const float var = (red[0] + red[1] + red[2] + red[3]) * (1.0f / (float)P_);
  const float inv = 1.0f / sqrtf(var + 1e-5f);
  out[b * P_ + tid] = dv * inv * gamma[tid] + beta[tid];
}

extern "C" void kernel_launch(void* const* d_in, const int* in_sizes, int n_in,
                              void* d_out, int out_size, void* d_ws, size_t ws_size,
                              hipStream_t stream) {
  (void)in_sizes; (void)n_in; (void)out_size; (void)ws_size;
  const float* hidden   = (const float*)d_in[0];  // [B,S,D]
  const float* attn     = (const float*)d_in[1];  // [B,H,S,S]
  /* d_in[2] = length (== S, unused) */
  const float* W_node   = (const float*)d_in[3];  // [D,P]
  const float* b_node   = (const float*)d_in[4];  // [P]
  const float* node_eta = (const float*)d_in[5];  // [1]
  const float* W_fc     = (const float*)d_in[6];  // [P,P]
  const float* b_fc     = (const float*)d_in[7];  // [P]
  const float* gamma    = (const float*)d_in[8];  // [P]
  const float* beta     = (const float*)d_in[9];  // [P]
  float* out = (float*)d_out;                     // [B,P] fp32

  float* w    = (float*)d_ws;            // B*S   edge-weight sums per source node
  float* x    = w + B_ * S_;             // B*D   coef-weighted hidden sums
  float* tbuf = x + B_ * D_;             // B*P   tanh(node_trans) pooled
  float* obuf = tbuf + B_ * P_;          // B*P   fc output
  hipMemsetAsync(d_ws, 0, (size_t)(B_ * S_ + B_ * D_) * sizeof(float), stream);

  k1_topk_weights<<<(B_ * S_) / 4, 256, 0, stream>>>(attn, w);
  k2_weighted_sum<<<dim3(NCHUNK_, B_), 192, 0, stream>>>(hidden, w, node_eta, x);
  k3a_tanh_matvec<<<dim3(8, B_), 256, 0, stream>>>(x, W_node, b_node, tbuf);
  k3b_fc<<<dim3(4, B_), 256, 0, stream>>>(tbuf, W_fc, b_fc, obuf);
  k3c_layernorm<<<B_, 256, 0, stream>>>(obuf, gamma, beta, out);
}